// Round 18
// baseline (286.246 us; speedup 1.0000x reference)
//
#include <hip/hip_runtime.h>
#include <hip/hip_bf16.h>

#define NN 8192
#define FF 512
#define HH 512
#define CC 64
#define NS_TOTAL 557056     // 512*512 + 512*512 + 64*512
#define KSEL 278529u        // 1 + round(0.5 * (557056-1))
#define MAXNBR 96
#define MASKB 2176          // NS_TOTAL / 256
#define NBINS 2048          // 11-bit radix digits (passes: bits [31:21],[20:10],[9:0])

typedef short short8 __attribute__((ext_vector_type(8)));
typedef __bf16 bf16x8 __attribute__((ext_vector_type(8)));
typedef float f32x4 __attribute__((ext_vector_type(4)));

__device__ __constant__ int kShift[3] = {21, 10, 0};

__device__ inline unsigned short f2bf(float f) {   // RNE f32 -> bf16 bits
    unsigned u = __float_as_uint(f);
    u += 0x7fffu + ((u >> 16) & 1u);
    return (unsigned short)(u >> 16);
}
__device__ inline float bf2f(unsigned short h) {
    return __uint_as_float(((unsigned)h) << 16);
}

__device__ inline f32x4 mfma16x16x32(short8 a, short8 b, f32x4 c) {
    return __builtin_amdgcn_mfma_f32_16x16x32_bf16(
        __builtin_bit_cast(bf16x8, a), __builtin_bit_cast(bf16x8, b), c, 0, 0, 0);
}

// async global->LDS, 16B per lane; LDS dest = wave-uniform base + lane*16
__device__ inline void gload_lds16(const unsigned short* g, unsigned short* l) {
    __builtin_amdgcn_global_load_lds(
        (const __attribute__((address_space(1))) void*)g,
        (__attribute__((address_space(3))) void*)l,
        16, 0, 0);
}

// ---- deg: one adjacency row per 256-thread block; also u[j] += dis[row] per neighbor j
// (uvec feeds the colsum identity in the spmm dispatch; ~17 scattered atomics/row = noise)
__device__ void deg_row_body(const float* __restrict__ adj, int* __restrict__ nnz,
                             int* __restrict__ colsI, float* __restrict__ dis,
                             float* __restrict__ uvec, int row, int* dcnt, float* dshare) {
    const int t = threadIdx.x;
    if (t == 0) *dcnt = 0;
    __syncthreads();
    const float4* arow = (const float4*)(adj + (size_t)row * NN);
    int* cp = colsI + (size_t)row * MAXNBR;
    for (int c4 = t; c4 < NN / 4; c4 += 256) {
        float4 v = arow[c4];
        int base = c4 * 4;
        float vv[4] = {v.x, v.y, v.z, v.w};
#pragma unroll
        for (int kq = 0; kq < 4; ++kq) {
            int col = base + kq;
            if (vv[kq] != 0.f || col == row) {
                int s = atomicAdd(dcnt, 1);
                if (s < MAXNBR) cp[s] = col;
            }
        }
    }
    __syncthreads();
    if (t == 0) {
        int c = *dcnt;
        int cl = (c < MAXNBR) ? c : MAXNBR;
        nnz[row] = cl;
        float d = rsqrtf((float)c);
        dis[row] = d;
        *dshare = d;
        *dcnt = cl;
    }
    __syncthreads();
    float dr = *dshare;
    int cl = *dcnt;
    if (t < cl) atomicAdd(&uvec[cp[t]], dr);
}

// ---- in-block select over 2048 bins (8 bins/thread): find bin with rank k ----
__device__ void isel2048(const unsigned* __restrict__ hist, unsigned k,
                         unsigned& bin, unsigned& krem) {
    __shared__ unsigned sh[256];
    __shared__ unsigned res[2];
    const int t = threadIdx.x;
    __syncthreads();                  // protect scratch from previous call
    unsigned g[8], sseg = 0;
#pragma unroll
    for (int i = 0; i < 8; ++i) { g[i] = hist[t * 8 + i]; sseg += g[i]; }
    sh[t] = sseg;
    __syncthreads();
    unsigned pre = 0;
    for (int i = 0; i < t; ++i) pre += sh[i];
    if (pre < k && k <= pre + sseg) {
        unsigned cum = pre;
        int i = 0;
        while (i < 7 && cum + g[i] < k) { cum += g[i]; ++i; }
        res[0] = (unsigned)(t * 8 + i);
        res[1] = k - cum;
    }
    __syncthreads();
    bin = res[0]; krem = res[1];
}

// derive threshold prefix through npass 11/11/10-bit digits
__device__ void isel_chain(const unsigned* __restrict__ hists, int npass,
                           unsigned& prefix, unsigned& k) {
    prefix = 0; k = KSEL;
    for (int p = 0; p < npass; ++p) {
        unsigned bin, krem;
        isel2048(hists + p * NBINS, k, bin, krem);
        prefix |= bin << kShift[p];
        k = krem;
    }
}

// ---------------- threshold histogram pass (blocks 0-255) + trailing deg blocks ---------

__global__ __launch_bounds__(256) void hist11_kernel(const float* __restrict__ S0,
                                                     const float* __restrict__ S1,
                                                     const float* __restrict__ S2,
                                                     unsigned* __restrict__ hists, int pass,
                                                     const float* __restrict__ adj,
                                                     int* __restrict__ nnz, int* __restrict__ colsI,
                                                     float* __restrict__ dis,
                                                     float* __restrict__ uvec, int degRow0) {
    __shared__ unsigned lh[NBINS];
    __shared__ int dcnt;
    __shared__ float dshare;
    if ((int)blockIdx.x >= 256) {
        deg_row_body(adj, nnz, colsI, dis, uvec, degRow0 + (int)blockIdx.x - 256,
                     &dcnt, &dshare);
        return;
    }
    unsigned prefix = 0, k;
    if (pass > 0) isel_chain(hists, pass, prefix, k);
    int shift = kShift[pass];
    // prefix = all bits above the PREVIOUS pass's digit start (r16 bug fixed in r17)
    unsigned pmask = pass ? (0xFFFFFFFFu << kShift[pass - 1]) : 0u;
    unsigned dmask = (pass == 2) ? 0x3FFu : 0x7FFu;
    __syncthreads();
    for (int i = threadIdx.x; i < NBINS; i += 256) lh[i] = 0;
    __syncthreads();
    for (int idx = blockIdx.x * 256 + threadIdx.x; idx < NS_TOTAL; idx += 65536) {
        float v = (idx < 262144) ? S0[idx] : (idx < 524288) ? S1[idx - 262144] : S2[idx - 524288];
        unsigned key = __float_as_uint(fabsf(v));
        if ((key & pmask) == prefix)
            atomicAdd(&lh[(key >> shift) & dmask], 1u);
    }
    __syncthreads();
    for (int i = threadIdx.x; i < NBINS; i += 256) {
        unsigned c = lh[i];
        if (c) atomicAdd(&hists[pass * NBINS + i], c);
    }
}

// ---------------- fused: masked weights -> hi/lo bf16  AND  x -> hi/lo bf16 ----------------

__global__ __launch_bounds__(256) void mask_split_fused(
        const float* __restrict__ W0, const float* __restrict__ W1,
        const float* __restrict__ W2, const float* __restrict__ S0,
        const float* __restrict__ S1, const float* __restrict__ S2,
        const unsigned* __restrict__ hists,
        unsigned short* __restrict__ W0h, unsigned short* __restrict__ W0l,
        unsigned short* __restrict__ W1h, unsigned short* __restrict__ W1l,
        unsigned short* __restrict__ W2h, unsigned short* __restrict__ W2l,
        const float* __restrict__ X,
        unsigned short* __restrict__ Xh, unsigned short* __restrict__ Xl) {
    if (blockIdx.x >= MASKB) {
        // ---- x split branch ----
        int i = (blockIdx.x - MASKB) * 256 + threadIdx.x;   // one float4; 4096 blocks
        float4 v = ((const float4*)X)[i];
        float vv[4] = {v.x, v.y, v.z, v.w};
        ushort4 hi, lo;
        unsigned short* hp = (unsigned short*)&hi;
        unsigned short* lp = (unsigned short*)&lo;
#pragma unroll
        for (int j = 0; j < 4; ++j) {
            hp[j] = f2bf(vv[j]);
            lp[j] = f2bf(vv[j] - bf2f(hp[j]));
        }
        *(ushort4*)&Xh[(size_t)i * 4] = hi;
        *(ushort4*)&Xl[(size_t)i * 4] = lo;
        return;
    }
    // ---- mask branch ----
    unsigned prefix, k;
    isel_chain(hists, 3, prefix, k);
    float thr = __uint_as_float(prefix);
    int idx = blockIdx.x * 256 + threadIdx.x;           // < NS_TOTAL exactly
    const float* W; const float* S; unsigned short* Yh; unsigned short* Yl; int i;
    if (idx < 262144)      { W = W0; S = S0; Yh = W0h; Yl = W0l; i = idx; }
    else if (idx < 524288) { W = W1; S = S1; Yh = W1h; Yl = W1l; i = idx - 262144; }
    else                   { W = W2; S = S2; Yh = W2h; Yl = W2l; i = idx - 524288; }
    float v = (fabsf(S[i]) > thr) ? W[i] : 0.f;
    unsigned short hi = f2bf(v);
    Yh[i] = hi;
    Yl[i] = f2bf(v - bf2f(hi));
}

// ---------------- hi/lo 3-term MFMA GEMM (single-buffer, r13-verified structure) ----------
// C = Ah*Bh^T + Ah*Bl^T + Al*Bh^T over K=512. BK=32, 4 waves (2x2).

template<int BMt, int BNt, int WRITE_SPLIT>
__global__ __launch_bounds__(256) void gemm_hl(
        const unsigned short* __restrict__ Ah, const unsigned short* __restrict__ Al,
        const unsigned short* __restrict__ Bh, const unsigned short* __restrict__ Bl,
        float* __restrict__ Cf, unsigned short* __restrict__ Ch,
        unsigned short* __restrict__ Cl, int Nn, int gridN) {
    constexpr int BK = 32;
    constexpr int MF = BMt / 32, NF = BNt / 32;
    __shared__ __align__(16) unsigned short AhS[BMt * BK], AlS[BMt * BK];
    __shared__ __align__(16) unsigned short BhS[BNt * BK], BlS[BNt * BK];

    const int tid = threadIdx.x, lane = tid & 63, wid = tid >> 6;
    const int wr = wid >> 1, wc = wid & 1;
    const int bm = ((int)blockIdx.x / gridN) * BMt;
    const int bn = ((int)blockIdx.x % gridN) * BNt;
    const int r16 = lane & 15, kg = lane >> 4;
    const int srow = lane >> 2;
    const int scol = ((lane & 3) ^ ((srow >> 1) & 3)) * 8;   // pre-swizzled source slot
    constexpr int cA = BMt / 16, cB = BNt / 16, CPW = (2 * cA + 2 * cB) / 4;
    f32x4 acc[MF][NF] = {};
    const int ksw = (kg ^ ((r16 >> 1) & 3)) * 8;             // read-side swizzle
    const unsigned short* pAh = &AhS[(wr * (BMt / 2) + r16) * BK + ksw];
    const unsigned short* pAl = &AlS[(wr * (BMt / 2) + r16) * BK + ksw];
    const unsigned short* pBh = &BhS[(wc * (BNt / 2) + r16) * BK + ksw];
    const unsigned short* pBl = &BlS[(wc * (BNt / 2) + r16) * BK + ksw];

    for (int k0 = 0; k0 < 512; k0 += BK) {
        __syncthreads();   // previous compute done reading LDS
#pragma unroll
        for (int i = 0; i < CPW; ++i) {
            int c = wid * CPW + i;
            const unsigned short* src; unsigned short* dst; int cc, r0;
            if (c < cA)               { src = Ah; dst = AhS; cc = c;               r0 = bm + cc * 16; }
            else if (c < 2 * cA)      { src = Al; dst = AlS; cc = c - cA;          r0 = bm + cc * 16; }
            else if (c < 2 * cA + cB) { src = Bh; dst = BhS; cc = c - 2 * cA;      r0 = bn + cc * 16; }
            else                      { src = Bl; dst = BlS; cc = c - 2 * cA - cB; r0 = bn + cc * 16; }
            gload_lds16(src + (size_t)(r0 + srow) * 512 + k0 + scol, dst + cc * 512);
        }
        __syncthreads();   // tiles resident
        short8 bhf[NF], blf[NF];
#pragma unroll
        for (int n = 0; n < NF; ++n) {
            bhf[n] = *(const short8*)(pBh + n * 16 * BK);
            blf[n] = *(const short8*)(pBl + n * 16 * BK);
        }
#pragma unroll
        for (int m = 0; m < MF; ++m) {
            short8 ahf = *(const short8*)(pAh + m * 16 * BK);
            short8 alf = *(const short8*)(pAl + m * 16 * BK);
#pragma unroll
            for (int n = 0; n < NF; ++n) {
                acc[m][n] = mfma16x16x32(ahf, bhf[n], acc[m][n]);
                acc[m][n] = mfma16x16x32(ahf, blf[n], acc[m][n]);
                acc[m][n] = mfma16x16x32(alf, bhf[n], acc[m][n]);
            }
        }
    }
    // epilogue: C/D layout col = lane&15, row = (lane>>4)*4 + j  [m89-verified]
#pragma unroll
    for (int m = 0; m < MF; ++m) {
#pragma unroll
        for (int n = 0; n < NF; ++n) {
            int row0 = bm + wr * (BMt / 2) + m * 16 + kg * 4;
            int col  = bn + wc * (BNt / 2) + n * 16 + r16;
#pragma unroll
            for (int j = 0; j < 4; ++j) {
                float v = acc[m][n][j];
                if (WRITE_SPLIT) {
                    unsigned short hi = f2bf(v);
                    size_t base = (size_t)(row0 + j) * Nn + col;
                    Ch[base] = hi;
                    Cl[base] = f2bf(v - bf2f(hi));
                } else {
                    Cf[(size_t)(row0 + j) * Nn + col] = v;
                }
            }
        }
    }
}

// ---------------- gemm3 with FUSED pairnorm+relu on the A side (r15-verified) ----------------

__global__ __launch_bounds__(256) void gemm3_pn(
        const float* __restrict__ hAgg,
        const unsigned short* __restrict__ Bh, const unsigned short* __restrict__ Bl,
        const float* __restrict__ colsum, const float* __restrict__ stats,
        float* __restrict__ Cf) {
    constexpr int BMt = 32, BNt = 64, BK = 32;
    constexpr int NF = 2;
    __shared__ __align__(16) unsigned short AhS[BMt * BK], AlS[BMt * BK];
    __shared__ __align__(16) unsigned short BhS[BNt * BK], BlS[BNt * BK];
    __shared__ float red[4];
    __shared__ float sbc;

    const int tid = threadIdx.x, lane = tid & 63, wid = tid >> 6;
    const int wr = wid >> 1, wc = wid & 1;
    const int bm = (int)blockIdx.x * BMt;          // bn = 0 (single N tile)
    const int r16 = lane & 15, kg = lane >> 4;
    const int srow = lane >> 2;
    const int scol = ((lane & 3) ^ ((srow >> 1) & 3)) * 8;
    const float inv = 1.0f / (float)NN;

    {
        float c0 = colsum[tid], c1 = colsum[tid + 256];
        float sq = c0 * c0 + c1 * c1;
#pragma unroll
        for (int o = 32; o > 0; o >>= 1) sq += __shfl_down(sq, o);
        if ((tid & 63) == 0) red[tid >> 6] = sq;
        __syncthreads();
        if (tid == 0) {
            float msum = red[0] + red[1] + red[2] + red[3];
            sbc = 1.0f / sqrtf(1e-6f + (stats[0] - msum * inv) * inv);
        }
        __syncthreads();
    }
    const float s = sbc;

    const int ar = tid >> 3, ac = (tid & 7) * 4;
    const int aoff = ar * 64 + (((ac >> 3) ^ ((ar >> 1) & 3)) * 16) + (ac & 7) * 2; // bytes

    f32x4 acc[1][NF] = {};
    const int ksw = (kg ^ ((r16 >> 1) & 3)) * 8;
    const unsigned short* pAh = &AhS[(wr * 16 + r16) * BK + ksw];
    const unsigned short* pAl = &AlS[(wr * 16 + r16) * BK + ksw];
    const unsigned short* pBh = &BhS[(wc * 32 + r16) * BK + ksw];
    const unsigned short* pBl = &BlS[(wc * 32 + r16) * BK + ksw];

    for (int k0 = 0; k0 < 512; k0 += BK) {
        __syncthreads();
#pragma unroll
        for (int i = 0; i < 2; ++i) {
            int c = wid * 2 + i;
            const unsigned short* src = (c < 4) ? Bh : Bl;
            unsigned short* dst = (c < 4) ? BhS : BlS;
            int cc = c & 3;
            gload_lds16(src + (size_t)(cc * 16 + srow) * 512 + k0 + scol, dst + cc * 512);
        }
        {
            float4 av = *(const float4*)(hAgg + (size_t)(bm + ar) * HH + k0 + ac);
            float4 m4 = *(const float4*)(colsum + k0 + ac);
            float vv[4];
            vv[0] = fmaxf((av.x - m4.x * inv) * s, 0.f);
            vv[1] = fmaxf((av.y - m4.y * inv) * s, 0.f);
            vv[2] = fmaxf((av.z - m4.z * inv) * s, 0.f);
            vv[3] = fmaxf((av.w - m4.w * inv) * s, 0.f);
            ushort4 hi, lo;
            unsigned short* hp = (unsigned short*)&hi;
            unsigned short* lp = (unsigned short*)&lo;
#pragma unroll
            for (int j = 0; j < 4; ++j) {
                hp[j] = f2bf(vv[j]);
                lp[j] = f2bf(vv[j] - bf2f(hp[j]));
            }
            *(ushort4*)((char*)AhS + aoff) = hi;
            *(ushort4*)((char*)AlS + aoff) = lo;
        }
        __syncthreads();
        short8 bhf[NF], blf[NF];
#pragma unroll
        for (int n = 0; n < NF; ++n) {
            bhf[n] = *(const short8*)(pBh + n * 16 * BK);
            blf[n] = *(const short8*)(pBl + n * 16 * BK);
        }
        short8 ahf = *(const short8*)pAh;
        short8 alf = *(const short8*)pAl;
#pragma unroll
        for (int n = 0; n < NF; ++n) {
            acc[0][n] = mfma16x16x32(ahf, bhf[n], acc[0][n]);
            acc[0][n] = mfma16x16x32(ahf, blf[n], acc[0][n]);
            acc[0][n] = mfma16x16x32(alf, bhf[n], acc[0][n]);
        }
    }
#pragma unroll
    for (int n = 0; n < NF; ++n) {
        int row0 = bm + wr * 16 + kg * 4;
        int col  = wc * 32 + n * 16 + r16;
#pragma unroll
        for (int j = 0; j < 4; ++j)
            Cf[(size_t)(row0 + j) * CC + col] = acc[0][n][j];
    }
}

// ---------------- SpMM dispatch: blocks <NN do spmm+sumsq; blocks >=NN do colsum-from-hB ----
// colsum_f = sum_j dis[j]*u[j]*hB[j,f]  (identity verified numerically in r14)

__global__ void spmm512_fused(const int* __restrict__ nnz, const int* __restrict__ colsI,
                              const float* __restrict__ dis, const float* __restrict__ uvec,
                              const float* __restrict__ Hin, float* __restrict__ Hout,
                              float* __restrict__ colsum, float* __restrict__ stats) {
    int t = threadIdx.x;  // 128
    if ((int)blockIdx.x >= NN) {
        // ---- colsum branch: 256 blocks, stride rows; 4 cols per thread ----
        int cb = (int)blockIdx.x - NN;
        float a0 = 0.f, a1 = 0.f, a2 = 0.f, a3 = 0.f;
        for (int j = cb; j < NN; j += 256) {
            float wj = dis[j] * uvec[j];
            const float* row = Hin + (size_t)j * HH;
            a0 += wj * row[t];
            a1 += wj * row[t + 128];
            a2 += wj * row[t + 256];
            a3 += wj * row[t + 384];
        }
        atomicAdd(&colsum[t], a0);
        atomicAdd(&colsum[t + 128], a1);
        atomicAdd(&colsum[t + 256], a2);
        atomicAdd(&colsum[t + 384], a3);
        return;
    }
    // ---- spmm branch (+ fused sum-of-squares of the produced row) ----
    int row = blockIdx.x;
    int cnt = nnz[row];
    const int* cp = colsI + (size_t)row * MAXNBR;
    float4 acc = make_float4(0.f, 0.f, 0.f, 0.f);
    for (int j = 0; j < cnt; ++j) {
        int c = cp[j];
        float wgt = dis[c];
        float4 v = *(const float4*)(Hin + (size_t)c * HH + t * 4);
        acc.x += wgt * v.x; acc.y += wgt * v.y; acc.z += wgt * v.z; acc.w += wgt * v.w;
    }
    float di = dis[row];
    acc.x *= di; acc.y *= di; acc.z *= di; acc.w *= di;
    *(float4*)(Hout + (size_t)row * HH + t * 4) = acc;
    float sq = acc.x * acc.x + acc.y * acc.y + acc.z * acc.z + acc.w * acc.w;
#pragma unroll
    for (int o = 32; o > 0; o >>= 1) sq += __shfl_down(sq, o);
    __shared__ float red[2];
    if ((t & 63) == 0) red[t >> 6] = sq;
    __syncthreads();
    if (t == 0) atomicAdd(stats, red[0] + red[1]);
}

__global__ void spmm64(const int* __restrict__ nnz, const int* __restrict__ colsI,
                       const float* __restrict__ dis, const float* __restrict__ Hin,
                       float* __restrict__ Hout) {
    int row = blockIdx.x;
    int t = threadIdx.x;  // 64
    int cnt = nnz[row];
    const int* cp = colsI + (size_t)row * MAXNBR;
    float acc = 0.f;
    for (int j = 0; j < cnt; ++j) {
        int c = cp[j];
        acc += dis[c] * Hin[(size_t)c * CC + t];
    }
    Hout[(size_t)row * CC + t] = dis[row] * acc;
}

// ---------------- launch ----------------

extern "C" void kernel_launch(void* const* d_in, const int* in_sizes, int n_in,
                              void* d_out, int out_size, void* d_ws, size_t ws_size,
                              hipStream_t stream) {
    const float* x   = (const float*)d_in[0];
    const float* adj = (const float*)d_in[1];
    const float* W0  = (const float*)d_in[2];
    const float* W1  = (const float*)d_in[3];
    const float* W2  = (const float*)d_in[4];
    const float* S0  = (const float*)d_in[5];
    const float* S1  = (const float*)d_in[6];
    const float* S2  = (const float*)d_in[7];
    float* out = (float*)d_out;

    char* w = (char*)d_ws;
    size_t off = 0;
    auto alloc = [&](size_t b) { size_t r = off; off = (off + b + 255) & ~(size_t)255; return r; };
    unsigned* hists = (unsigned*)(w + alloc(3 * NBINS * 4));   // hists[pass][2048]
    float* colsum   = (float*)(w + alloc(HH * 4));
    float* stats    = (float*)(w + alloc(256));
    float* uvec     = (float*)(w + alloc(NN * 4));             // u[j] = sum_r A[r,j]*dis[r]
    size_t zero_end = off;
    int* nnz   = (int*)(w + alloc(NN * 4));
    int* colsI = (int*)(w + alloc((size_t)NN * MAXNBR * 4));
    float* dis = (float*)(w + alloc(NN * 4));
    unsigned short* xh  = (unsigned short*)(w + alloc((size_t)NN * FF * 2));
    unsigned short* xl  = (unsigned short*)(w + alloc((size_t)NN * FF * 2));
    unsigned short* W0h = (unsigned short*)(w + alloc((size_t)HH * FF * 2));
    unsigned short* W0l = (unsigned short*)(w + alloc((size_t)HH * FF * 2));
    unsigned short* W1h = (unsigned short*)(w + alloc((size_t)HH * HH * 2));
    unsigned short* W1l = (unsigned short*)(w + alloc((size_t)HH * HH * 2));
    unsigned short* W2h = (unsigned short*)(w + alloc((size_t)CC * HH * 2));
    unsigned short* W2l = (unsigned short*)(w + alloc((size_t)CC * HH * 2));
    unsigned short* hAh = (unsigned short*)(w + alloc((size_t)NN * HH * 2));
    unsigned short* hAl = (unsigned short*)(w + alloc((size_t)NN * HH * 2));
    float* hB   = (float*)(w + alloc((size_t)NN * HH * 4));
    float* hAgg = (float*)(w + alloc((size_t)NN * HH * 4));
    float* h3   = (float*)(w + alloc((size_t)NN * CC * 4));
    (void)ws_size; (void)in_sizes; (void)n_in; (void)out_size;

    hipMemsetAsync(d_ws, 0, zero_end, stream);

    // threshold: 3 x 11/11/10-bit histogram passes, each carrying ~2731 deg blocks
    // (ALL 8192 adjacency rows + uvec accumulation complete before spmm512)
    const int degPer[3] = {2731, 2731, 2730};
    int degBase = 0;
    for (int p = 0; p < 3; ++p) {
        hist11_kernel<<<256 + degPer[p], 256, 0, stream>>>(S0, S1, S2, hists, p,
                                                           adj, nnz, colsI, dis, uvec, degBase);
        degBase += degPer[p];
    }

    // fused: masked weights -> hi/lo bf16  AND  x -> hi/lo bf16
    mask_split_fused<<<MASKB + NN * FF / 4 / 256, 256, 0, stream>>>(
        W0, W1, W2, S0, S1, S2, hists, W0h, W0l, W1h, W1l, W2h, W2l, x, xh, xl);

    // gemms (r13-verified single-buffer structure)
    gemm_hl<64, 128, 1><<<(NN / 64) * (HH / 128), 256, 0, stream>>>(
        xh, xl, W0h, W0l, nullptr, hAh, hAl, HH, HH / 128);
    gemm_hl<64, 128, 0><<<(NN / 64) * (HH / 128), 256, 0, stream>>>(
        hAh, hAl, W1h, W1l, hB, nullptr, nullptr, HH, HH / 128);

    // aggregation + fused sumsq + colsum-from-hB (identity) -> kills the colstats dispatch
    spmm512_fused<<<NN + 256, 128, 0, stream>>>(nnz, colsI, dis, uvec, hB, hAgg,
                                                colsum, stats);

    // gemm3 with fused pairnorm+relu+split on the A side ; out = adj_n @ h3
    gemm3_pn<<<NN / 32, 256, 0, stream>>>(hAgg, W2h, W2l, colsum, stats, h3);
    spmm64<<<NN, 64, 0, stream>>>(nnz, colsI, dis, h3, out);
}

// Round 19
// 211.472 us; speedup vs baseline: 1.3536x; 1.3536x over previous
//
#include <hip/hip_runtime.h>
#include <hip/hip_bf16.h>

#define NN 8192
#define FF 512
#define HH 512
#define CC 64
#define NS_TOTAL 557056     // 512*512 + 512*512 + 64*512
#define KSEL 278529u        // 1 + round(0.5 * (557056-1))
#define MAXNBR 96
#define MASKB 2176          // NS_TOTAL / 256
#define NBINS 2048          // 11-bit radix digits (passes: bits [31:21],[20:10],[9:0])

typedef short short8 __attribute__((ext_vector_type(8)));
typedef __bf16 bf16x8 __attribute__((ext_vector_type(8)));
typedef float f32x4 __attribute__((ext_vector_type(4)));

__device__ __constant__ int kShift[3] = {21, 10, 0};

__device__ inline unsigned short f2bf(float f) {   // RNE f32 -> bf16 bits
    unsigned u = __float_as_uint(f);
    u += 0x7fffu + ((u >> 16) & 1u);
    return (unsigned short)(u >> 16);
}
__device__ inline float bf2f(unsigned short h) {
    return __uint_as_float(((unsigned)h) << 16);
}

__device__ inline f32x4 mfma16x16x32(short8 a, short8 b, f32x4 c) {
    return __builtin_amdgcn_mfma_f32_16x16x32_bf16(
        __builtin_bit_cast(bf16x8, a), __builtin_bit_cast(bf16x8, b), c, 0, 0, 0);
}

// async global->LDS, 16B per lane; LDS dest = wave-uniform base + lane*16
__device__ inline void gload_lds16(const unsigned short* g, unsigned short* l) {
    __builtin_amdgcn_global_load_lds(
        (const __attribute__((address_space(1))) void*)g,
        (__attribute__((address_space(3))) void*)l,
        16, 0, 0);
}

// ---- deg: one adjacency row processed by one 256-thread block ----
// NOTE (r14/r18 lesson): do NOT add scattered uvec atomics here — twice measured at +70-100us.
__device__ void deg_row_body(const float* __restrict__ adj, int* __restrict__ nnz,
                             int* __restrict__ colsI, float* __restrict__ dis,
                             int row, int* dcnt) {
    const int t = threadIdx.x;
    if (t == 0) *dcnt = 0;
    __syncthreads();
    const float4* arow = (const float4*)(adj + (size_t)row * NN);
    int* cp = colsI + (size_t)row * MAXNBR;
    for (int c4 = t; c4 < NN / 4; c4 += 256) {
        float4 v = arow[c4];
        int base = c4 * 4;
        float vv[4] = {v.x, v.y, v.z, v.w};
#pragma unroll
        for (int kq = 0; kq < 4; ++kq) {
            int col = base + kq;
            if (vv[kq] != 0.f || col == row) {
                int s = atomicAdd(dcnt, 1);
                if (s < MAXNBR) cp[s] = col;
            }
        }
    }
    __syncthreads();
    if (t == 0) {
        int c = *dcnt;
        nnz[row] = (c < MAXNBR) ? c : MAXNBR;
        dis[row] = rsqrtf((float)c);
    }
}

// ---- in-block select over 2048 bins (8 bins/thread): find bin with rank k ----
__device__ void isel2048(const unsigned* __restrict__ hist, unsigned k,
                         unsigned& bin, unsigned& krem) {
    __shared__ unsigned sh[256];
    __shared__ unsigned res[2];
    const int t = threadIdx.x;
    __syncthreads();                  // protect scratch from previous call
    unsigned g[8], sseg = 0;
#pragma unroll
    for (int i = 0; i < 8; ++i) { g[i] = hist[t * 8 + i]; sseg += g[i]; }
    sh[t] = sseg;
    __syncthreads();
    unsigned pre = 0;
    for (int i = 0; i < t; ++i) pre += sh[i];
    if (pre < k && k <= pre + sseg) {
        unsigned cum = pre;
        int i = 0;
        while (i < 7 && cum + g[i] < k) { cum += g[i]; ++i; }
        res[0] = (unsigned)(t * 8 + i);
        res[1] = k - cum;
    }
    __syncthreads();
    bin = res[0]; krem = res[1];
}

// derive threshold prefix through npass 11/11/10-bit digits
__device__ void isel_chain(const unsigned* __restrict__ hists, int npass,
                           unsigned& prefix, unsigned& k) {
    prefix = 0; k = KSEL;
    for (int p = 0; p < npass; ++p) {
        unsigned bin, krem;
        isel2048(hists + p * NBINS, k, bin, krem);
        prefix |= bin << kShift[p];
        k = krem;
    }
}

// ---------------- threshold histogram pass (blocks 0-255) + trailing deg blocks ---------

__global__ __launch_bounds__(256) void hist11_kernel(const float* __restrict__ S0,
                                                     const float* __restrict__ S1,
                                                     const float* __restrict__ S2,
                                                     unsigned* __restrict__ hists, int pass,
                                                     const float* __restrict__ adj,
                                                     int* __restrict__ nnz, int* __restrict__ colsI,
                                                     float* __restrict__ dis, int degRow0) {
    __shared__ unsigned lh[NBINS];
    __shared__ int dcnt;
    if ((int)blockIdx.x >= 256) {
        deg_row_body(adj, nnz, colsI, dis, degRow0 + (int)blockIdx.x - 256, &dcnt);
        return;
    }
    unsigned prefix = 0, k;
    if (pass > 0) isel_chain(hists, pass, prefix, k);
    int shift = kShift[pass];
    // prefix = all bits above the PREVIOUS pass's digit start (r16 bug fixed in r17)
    unsigned pmask = pass ? (0xFFFFFFFFu << kShift[pass - 1]) : 0u;
    unsigned dmask = (pass == 2) ? 0x3FFu : 0x7FFu;
    __syncthreads();
    for (int i = threadIdx.x; i < NBINS; i += 256) lh[i] = 0;
    __syncthreads();
    for (int idx = blockIdx.x * 256 + threadIdx.x; idx < NS_TOTAL; idx += 65536) {
        float v = (idx < 262144) ? S0[idx] : (idx < 524288) ? S1[idx - 262144] : S2[idx - 524288];
        unsigned key = __float_as_uint(fabsf(v));
        if ((key & pmask) == prefix)
            atomicAdd(&lh[(key >> shift) & dmask], 1u);
    }
    __syncthreads();
    for (int i = threadIdx.x; i < NBINS; i += 256) {
        unsigned c = lh[i];
        if (c) atomicAdd(&hists[pass * NBINS + i], c);
    }
}

// ---------------- fused: masked weights -> hi/lo bf16  AND  x -> hi/lo bf16 ----------------

__global__ __launch_bounds__(256) void mask_split_fused(
        const float* __restrict__ W0, const float* __restrict__ W1,
        const float* __restrict__ W2, const float* __restrict__ S0,
        const float* __restrict__ S1, const float* __restrict__ S2,
        const unsigned* __restrict__ hists,
        unsigned short* __restrict__ W0h, unsigned short* __restrict__ W0l,
        unsigned short* __restrict__ W1h, unsigned short* __restrict__ W1l,
        unsigned short* __restrict__ W2h, unsigned short* __restrict__ W2l,
        const float* __restrict__ X,
        unsigned short* __restrict__ Xh, unsigned short* __restrict__ Xl) {
    if (blockIdx.x >= MASKB) {
        // ---- x split branch ----
        int i = (blockIdx.x - MASKB) * 256 + threadIdx.x;   // one float4; 4096 blocks
        float4 v = ((const float4*)X)[i];
        float vv[4] = {v.x, v.y, v.z, v.w};
        ushort4 hi, lo;
        unsigned short* hp = (unsigned short*)&hi;
        unsigned short* lp = (unsigned short*)&lo;
#pragma unroll
        for (int j = 0; j < 4; ++j) {
            hp[j] = f2bf(vv[j]);
            lp[j] = f2bf(vv[j] - bf2f(hp[j]));
        }
        *(ushort4*)&Xh[(size_t)i * 4] = hi;
        *(ushort4*)&Xl[(size_t)i * 4] = lo;
        return;
    }
    // ---- mask branch ----
    unsigned prefix, k;
    isel_chain(hists, 3, prefix, k);
    float thr = __uint_as_float(prefix);
    int idx = blockIdx.x * 256 + threadIdx.x;           // < NS_TOTAL exactly
    const float* W; const float* S; unsigned short* Yh; unsigned short* Yl; int i;
    if (idx < 262144)      { W = W0; S = S0; Yh = W0h; Yl = W0l; i = idx; }
    else if (idx < 524288) { W = W1; S = S1; Yh = W1h; Yl = W1l; i = idx - 262144; }
    else                   { W = W2; S = S2; Yh = W2h; Yl = W2l; i = idx - 524288; }
    float v = (fabsf(S[i]) > thr) ? W[i] : 0.f;
    unsigned short hi = f2bf(v);
    Yh[i] = hi;
    Yl[i] = f2bf(v - bf2f(hi));
}

// ---------------- hi/lo 3-term MFMA GEMM (single-buffer, r13-verified structure) ----------
// C = Ah*Bh^T + Ah*Bl^T + Al*Bh^T over K=512. BK=32, 4 waves (2x2).

template<int BMt, int BNt, int WRITE_SPLIT>
__global__ __launch_bounds__(256) void gemm_hl(
        const unsigned short* __restrict__ Ah, const unsigned short* __restrict__ Al,
        const unsigned short* __restrict__ Bh, const unsigned short* __restrict__ Bl,
        float* __restrict__ Cf, unsigned short* __restrict__ Ch,
        unsigned short* __restrict__ Cl, int Nn, int gridN) {
    constexpr int BK = 32;
    constexpr int MF = BMt / 32, NF = BNt / 32;
    __shared__ __align__(16) unsigned short AhS[BMt * BK], AlS[BMt * BK];
    __shared__ __align__(16) unsigned short BhS[BNt * BK], BlS[BNt * BK];

    const int tid = threadIdx.x, lane = tid & 63, wid = tid >> 6;
    const int wr = wid >> 1, wc = wid & 1;
    const int bm = ((int)blockIdx.x / gridN) * BMt;
    const int bn = ((int)blockIdx.x % gridN) * BNt;
    const int r16 = lane & 15, kg = lane >> 4;
    const int srow = lane >> 2;
    const int scol = ((lane & 3) ^ ((srow >> 1) & 3)) * 8;   // pre-swizzled source slot
    constexpr int cA = BMt / 16, cB = BNt / 16, CPW = (2 * cA + 2 * cB) / 4;
    f32x4 acc[MF][NF] = {};
    const int ksw = (kg ^ ((r16 >> 1) & 3)) * 8;             // read-side swizzle
    const unsigned short* pAh = &AhS[(wr * (BMt / 2) + r16) * BK + ksw];
    const unsigned short* pAl = &AlS[(wr * (BMt / 2) + r16) * BK + ksw];
    const unsigned short* pBh = &BhS[(wc * (BNt / 2) + r16) * BK + ksw];
    const unsigned short* pBl = &BlS[(wc * (BNt / 2) + r16) * BK + ksw];

    for (int k0 = 0; k0 < 512; k0 += BK) {
        __syncthreads();   // previous compute done reading LDS
#pragma unroll
        for (int i = 0; i < CPW; ++i) {
            int c = wid * CPW + i;
            const unsigned short* src; unsigned short* dst; int cc, r0;
            if (c < cA)               { src = Ah; dst = AhS; cc = c;               r0 = bm + cc * 16; }
            else if (c < 2 * cA)      { src = Al; dst = AlS; cc = c - cA;          r0 = bm + cc * 16; }
            else if (c < 2 * cA + cB) { src = Bh; dst = BhS; cc = c - 2 * cA;      r0 = bn + cc * 16; }
            else                      { src = Bl; dst = BlS; cc = c - 2 * cA - cB; r0 = bn + cc * 16; }
            gload_lds16(src + (size_t)(r0 + srow) * 512 + k0 + scol, dst + cc * 512);
        }
        __syncthreads();   // tiles resident
        short8 bhf[NF], blf[NF];
#pragma unroll
        for (int n = 0; n < NF; ++n) {
            bhf[n] = *(const short8*)(pBh + n * 16 * BK);
            blf[n] = *(const short8*)(pBl + n * 16 * BK);
        }
#pragma unroll
        for (int m = 0; m < MF; ++m) {
            short8 ahf = *(const short8*)(pAh + m * 16 * BK);
            short8 alf = *(const short8*)(pAl + m * 16 * BK);
#pragma unroll
            for (int n = 0; n < NF; ++n) {
                acc[m][n] = mfma16x16x32(ahf, bhf[n], acc[m][n]);
                acc[m][n] = mfma16x16x32(ahf, blf[n], acc[m][n]);
                acc[m][n] = mfma16x16x32(alf, bhf[n], acc[m][n]);
            }
        }
    }
    // epilogue: C/D layout col = lane&15, row = (lane>>4)*4 + j  [m89-verified]
#pragma unroll
    for (int m = 0; m < MF; ++m) {
#pragma unroll
        for (int n = 0; n < NF; ++n) {
            int row0 = bm + wr * (BMt / 2) + m * 16 + kg * 4;
            int col  = bn + wc * (BNt / 2) + n * 16 + r16;
#pragma unroll
            for (int j = 0; j < 4; ++j) {
                float v = acc[m][n][j];
                if (WRITE_SPLIT) {
                    unsigned short hi = f2bf(v);
                    size_t base = (size_t)(row0 + j) * Nn + col;
                    Ch[base] = hi;
                    Cl[base] = f2bf(v - bf2f(hi));
                } else {
                    Cf[(size_t)(row0 + j) * Nn + col] = v;
                }
            }
        }
    }
}

// ---------------- gemm3 with FUSED pairnorm+relu on the A side (r15-verified) ----------------

__global__ __launch_bounds__(256) void gemm3_pn(
        const float* __restrict__ hAgg,
        const unsigned short* __restrict__ Bh, const unsigned short* __restrict__ Bl,
        const float* __restrict__ colsum, const float* __restrict__ stats,
        float* __restrict__ Cf) {
    constexpr int BMt = 32, BNt = 64, BK = 32;
    constexpr int NF = 2;
    __shared__ __align__(16) unsigned short AhS[BMt * BK], AlS[BMt * BK];
    __shared__ __align__(16) unsigned short BhS[BNt * BK], BlS[BNt * BK];
    __shared__ float red[4];
    __shared__ float sbc;

    const int tid = threadIdx.x, lane = tid & 63, wid = tid >> 6;
    const int wr = wid >> 1, wc = wid & 1;
    const int bm = (int)blockIdx.x * BMt;          // bn = 0 (single N tile)
    const int r16 = lane & 15, kg = lane >> 4;
    const int srow = lane >> 2;
    const int scol = ((lane & 3) ^ ((srow >> 1) & 3)) * 8;
    const float inv = 1.0f / (float)NN;

    {
        float c0 = colsum[tid], c1 = colsum[tid + 256];
        float sq = c0 * c0 + c1 * c1;
#pragma unroll
        for (int o = 32; o > 0; o >>= 1) sq += __shfl_down(sq, o);
        if ((tid & 63) == 0) red[tid >> 6] = sq;
        __syncthreads();
        if (tid == 0) {
            float msum = red[0] + red[1] + red[2] + red[3];
            sbc = 1.0f / sqrtf(1e-6f + (stats[0] - msum * inv) * inv);
        }
        __syncthreads();
    }
    const float s = sbc;

    const int ar = tid >> 3, ac = (tid & 7) * 4;
    const int aoff = ar * 64 + (((ac >> 3) ^ ((ar >> 1) & 3)) * 16) + (ac & 7) * 2; // bytes

    f32x4 acc[1][NF] = {};
    const int ksw = (kg ^ ((r16 >> 1) & 3)) * 8;
    const unsigned short* pAh = &AhS[(wr * 16 + r16) * BK + ksw];
    const unsigned short* pAl = &AlS[(wr * 16 + r16) * BK + ksw];
    const unsigned short* pBh = &BhS[(wc * 32 + r16) * BK + ksw];
    const unsigned short* pBl = &BlS[(wc * 32 + r16) * BK + ksw];

    for (int k0 = 0; k0 < 512; k0 += BK) {
        __syncthreads();
#pragma unroll
        for (int i = 0; i < 2; ++i) {
            int c = wid * 2 + i;
            const unsigned short* src = (c < 4) ? Bh : Bl;
            unsigned short* dst = (c < 4) ? BhS : BlS;
            int cc = c & 3;
            gload_lds16(src + (size_t)(cc * 16 + srow) * 512 + k0 + scol, dst + cc * 512);
        }
        {
            float4 av = *(const float4*)(hAgg + (size_t)(bm + ar) * HH + k0 + ac);
            float4 m4 = *(const float4*)(colsum + k0 + ac);
            float vv[4];
            vv[0] = fmaxf((av.x - m4.x * inv) * s, 0.f);
            vv[1] = fmaxf((av.y - m4.y * inv) * s, 0.f);
            vv[2] = fmaxf((av.z - m4.z * inv) * s, 0.f);
            vv[3] = fmaxf((av.w - m4.w * inv) * s, 0.f);
            ushort4 hi, lo;
            unsigned short* hp = (unsigned short*)&hi;
            unsigned short* lp = (unsigned short*)&lo;
#pragma unroll
            for (int j = 0; j < 4; ++j) {
                hp[j] = f2bf(vv[j]);
                lp[j] = f2bf(vv[j] - bf2f(hp[j]));
            }
            *(ushort4*)((char*)AhS + aoff) = hi;
            *(ushort4*)((char*)AlS + aoff) = lo;
        }
        __syncthreads();
        short8 bhf[NF], blf[NF];
#pragma unroll
        for (int n = 0; n < NF; ++n) {
            bhf[n] = *(const short8*)(pBh + n * 16 * BK);
            blf[n] = *(const short8*)(pBl + n * 16 * BK);
        }
        short8 ahf = *(const short8*)pAh;
        short8 alf = *(const short8*)pAl;
#pragma unroll
        for (int n = 0; n < NF; ++n) {
            acc[0][n] = mfma16x16x32(ahf, bhf[n], acc[0][n]);
            acc[0][n] = mfma16x16x32(ahf, blf[n], acc[0][n]);
            acc[0][n] = mfma16x16x32(alf, bhf[n], acc[0][n]);
        }
    }
#pragma unroll
    for (int n = 0; n < NF; ++n) {
        int row0 = bm + wr * 16 + kg * 4;
        int col  = wc * 32 + n * 16 + r16;
#pragma unroll
        for (int j = 0; j < 4; ++j)
            Cf[(size_t)(row0 + j) * CC + col] = acc[0][n][j];
    }
}

// ---------------- SpMM: Hout[row,:] = dis[row] * sum_nbr dis[c] * Hin[c,:] ----------------

__global__ void spmm512(const int* __restrict__ nnz, const int* __restrict__ colsI,
                        const float* __restrict__ dis, const float* __restrict__ Hin,
                        float* __restrict__ Hout) {
    int row = blockIdx.x;
    int t = threadIdx.x;  // 128
    int cnt = nnz[row];
    const int* cp = colsI + (size_t)row * MAXNBR;
    float4 acc = make_float4(0.f, 0.f, 0.f, 0.f);
    for (int j = 0; j < cnt; ++j) {
        int c = cp[j];
        float wgt = dis[c];
        float4 v = *(const float4*)(Hin + (size_t)c * HH + t * 4);
        acc.x += wgt * v.x; acc.y += wgt * v.y; acc.z += wgt * v.z; acc.w += wgt * v.w;
    }
    float di = dis[row];
    acc.x *= di; acc.y *= di; acc.z *= di; acc.w *= di;
    *(float4*)(Hout + (size_t)row * HH + t * 4) = acc;
}

__global__ void spmm64(const int* __restrict__ nnz, const int* __restrict__ colsI,
                       const float* __restrict__ dis, const float* __restrict__ Hin,
                       float* __restrict__ Hout) {
    int row = blockIdx.x;
    int t = threadIdx.x;  // 64
    int cnt = nnz[row];
    const int* cp = colsI + (size_t)row * MAXNBR;
    float acc = 0.f;
    for (int j = 0; j < cnt; ++j) {
        int c = cp[j];
        acc += dis[c] * Hin[(size_t)c * CC + t];
    }
    Hout[(size_t)row * CC + t] = dis[row] * acc;
}

// ---------------- PairNorm stats: colsum + total sum-of-squares in one pass ----------

__global__ void colstats_kernel(const float* __restrict__ X, float* __restrict__ colsum,
                                float* __restrict__ stats) {
    int t = threadIdx.x;  // 256 threads, 256 blocks
    float s0 = 0.f, s1 = 0.f, sq = 0.f;
    for (int r = blockIdx.x; r < NN; r += 256) {
        const float* row = X + (size_t)r * HH;
        float a = row[t], b = row[t + 256];
        s0 += a; s1 += b;
        sq += a * a + b * b;
    }
    atomicAdd(&colsum[t], s0);
    atomicAdd(&colsum[t + 256], s1);
#pragma unroll
    for (int o = 32; o > 0; o >>= 1) sq += __shfl_down(sq, o);
    __shared__ float red[4];
    int wv = t >> 6, lane = t & 63;
    if (lane == 0) red[wv] = sq;
    __syncthreads();
    if (t == 0) atomicAdd(stats, red[0] + red[1] + red[2] + red[3]);
}

// ---------------- launch ----------------

extern "C" void kernel_launch(void* const* d_in, const int* in_sizes, int n_in,
                              void* d_out, int out_size, void* d_ws, size_t ws_size,
                              hipStream_t stream) {
    const float* x   = (const float*)d_in[0];
    const float* adj = (const float*)d_in[1];
    const float* W0  = (const float*)d_in[2];
    const float* W1  = (const float*)d_in[3];
    const float* W2  = (const float*)d_in[4];
    const float* S0  = (const float*)d_in[5];
    const float* S1  = (const float*)d_in[6];
    const float* S2  = (const float*)d_in[7];
    float* out = (float*)d_out;

    char* w = (char*)d_ws;
    size_t off = 0;
    auto alloc = [&](size_t b) { size_t r = off; off = (off + b + 255) & ~(size_t)255; return r; };
    unsigned* hists = (unsigned*)(w + alloc(3 * NBINS * 4));   // hists[pass][2048]
    float* colsum   = (float*)(w + alloc(HH * 4));
    float* stats    = (float*)(w + alloc(256));
    size_t zero_end = off;
    int* nnz   = (int*)(w + alloc(NN * 4));
    int* colsI = (int*)(w + alloc((size_t)NN * MAXNBR * 4));
    float* dis = (float*)(w + alloc(NN * 4));
    unsigned short* xh  = (unsigned short*)(w + alloc((size_t)NN * FF * 2));
    unsigned short* xl  = (unsigned short*)(w + alloc((size_t)NN * FF * 2));
    unsigned short* W0h = (unsigned short*)(w + alloc((size_t)HH * FF * 2));
    unsigned short* W0l = (unsigned short*)(w + alloc((size_t)HH * FF * 2));
    unsigned short* W1h = (unsigned short*)(w + alloc((size_t)HH * HH * 2));
    unsigned short* W1l = (unsigned short*)(w + alloc((size_t)HH * HH * 2));
    unsigned short* W2h = (unsigned short*)(w + alloc((size_t)CC * HH * 2));
    unsigned short* W2l = (unsigned short*)(w + alloc((size_t)CC * HH * 2));
    unsigned short* hAh = (unsigned short*)(w + alloc((size_t)NN * HH * 2));
    unsigned short* hAl = (unsigned short*)(w + alloc((size_t)NN * HH * 2));
    float* hB   = (float*)(w + alloc((size_t)NN * HH * 4));
    float* hAgg = (float*)(w + alloc((size_t)NN * HH * 4));
    float* h3   = (float*)(w + alloc((size_t)NN * CC * 4));
    (void)ws_size; (void)in_sizes; (void)n_in; (void)out_size;

    hipMemsetAsync(d_ws, 0, zero_end, stream);

    // threshold: 3 x 11/11/10-bit histogram passes, each carrying ~2731 deg blocks
    // (ALL 8192 adjacency rows processed here -> gemm kernels are pure)
    const int degPer[3] = {2731, 2731, 2730};
    int degBase = 0;
    for (int p = 0; p < 3; ++p) {
        hist11_kernel<<<256 + degPer[p], 256, 0, stream>>>(S0, S1, S2, hists, p,
                                                           adj, nnz, colsI, dis, degBase);
        degBase += degPer[p];
    }

    // fused: masked weights -> hi/lo bf16  AND  x -> hi/lo bf16
    mask_split_fused<<<MASKB + NN * FF / 4 / 256, 256, 0, stream>>>(
        W0, W1, W2, S0, S1, S2, hists, W0h, W0l, W1h, W1l, W2h, W2l, x, xh, xl);

    // gemms (r13-verified single-buffer structure)
    gemm_hl<64, 128, 1><<<(NN / 64) * (HH / 128), 256, 0, stream>>>(
        xh, xl, W0h, W0l, nullptr, hAh, hAl, HH, HH / 128);
    gemm_hl<64, 128, 0><<<(NN / 64) * (HH / 128), 256, 0, stream>>>(
        hAh, hAl, W1h, W1l, hB, nullptr, nullptr, HH, HH / 128);

    // aggregation
    spmm512<<<NN, 128, 0, stream>>>(nnz, colsI, dis, hB, hAgg);

    // pairnorm stats (single fused pass)
    colstats_kernel<<<256, 256, 0, stream>>>(hAgg, colsum, stats);

    // gemm3 with fused pairnorm+relu+split on the A side ; out = adj_n @ h3
    gemm3_pn<<<NN / 32, 256, 0, stream>>>(hAgg, W2h, W2l, colsum, stats, h3);
    spmm64<<<NN, 64, 0, stream>>>(nnz, colsI, dis, h3, out);
}